// Round 1
// baseline (338.672 us; speedup 1.0000x reference)
//
#include <hip/hip_runtime.h>

// Problem constants (fixed by the reference setup)
#define NN    2048
#define BATCH 8
#define FIN   16
#define TT    12
#define FOUT  32
#define FT    (FIN*TT)    // 192
#define OT    (FOUT*TT)   // 384

typedef unsigned short ushort_t;
typedef __attribute__((ext_vector_type(8))) short   short8;
typedef __attribute__((ext_vector_type(4))) float   f32x4;
typedef __attribute__((ext_vector_type(4))) unsigned short us4;
typedef __attribute__((ext_vector_type(8))) unsigned short us8;

__device__ __forceinline__ float b2f(unsigned short u) {
    union { unsigned int i; float f; } v; v.i = ((unsigned int)u) << 16; return v.f;
}
__device__ __forceinline__ unsigned short f2b(float f) {
    union { float f; unsigned int i; } v; v.f = f;
    unsigned int x = v.i;
    x += 0x7fffu + ((x >> 16) & 1u);   // RTNE
    return (unsigned short)(x >> 16);
}

// ---------------------------------------------------------------------------
// Phase 1: S = softmax(relu(E E^T), axis=1), written directly as bf16 (Sb)
// E loads vectorized (f32x4): rows are 64 B, perfectly aligned.
// ---------------------------------------------------------------------------
__global__ __launch_bounds__(256)
void k_supports(const float* __restrict__ E, ushort_t* __restrict__ Sb) {
    const int n = blockIdx.x;
    __shared__ float row[NN];
    __shared__ float red[256];
    const int tid = threadIdx.x;

    const f32x4 en0 = *(const f32x4*)&E[n * 16 + 0];
    const f32x4 en1 = *(const f32x4*)&E[n * 16 + 4];
    const f32x4 en2 = *(const f32x4*)&E[n * 16 + 8];
    const f32x4 en3 = *(const f32x4*)&E[n * 16 + 12];

    float lmax = 0.0f;  // relu output >= 0
    for (int m = tid; m < NN; m += 256) {
        const f32x4* Em = (const f32x4*)&E[(size_t)m * 16];
        const f32x4 e0 = Em[0], e1 = Em[1], e2 = Em[2], e3 = Em[3];
        float d = 0.0f;
        #pragma unroll
        for (int j = 0; j < 4; ++j) d += en0[j] * e0[j];
        #pragma unroll
        for (int j = 0; j < 4; ++j) d += en1[j] * e1[j];
        #pragma unroll
        for (int j = 0; j < 4; ++j) d += en2[j] * e2[j];
        #pragma unroll
        for (int j = 0; j < 4; ++j) d += en3[j] * e3[j];
        d = fmaxf(d, 0.0f);
        row[m] = d;
        lmax = fmaxf(lmax, d);
    }
    red[tid] = lmax; __syncthreads();
    for (int s = 128; s > 0; s >>= 1) {
        if (tid < s) red[tid] = fmaxf(red[tid], red[tid + s]);
        __syncthreads();
    }
    const float mx = red[0];
    __syncthreads();

    float lsum = 0.0f;
    for (int m = tid; m < NN; m += 256) {
        float e = __expf(row[m] - mx);
        row[m] = e;
        lsum += e;
    }
    red[tid] = lsum; __syncthreads();
    for (int s = 128; s > 0; s >>= 1) {
        if (tid < s) red[tid] += red[tid + s];
        __syncthreads();
    }
    const float inv = 1.0f / red[0];
    for (int m = tid; m < NN; m += 256) Sb[(size_t)n * NN + m] = f2b(row[m] * inv);
}

// ---------------------------------------------------------------------------
// Pack: SbT[m][n] = Sb[n][m]   (tile transpose, bf16)
// ---------------------------------------------------------------------------
__global__ __launch_bounds__(256)
void k_pack_st(const ushort_t* __restrict__ Sb, ushort_t* __restrict__ SbT) {
    const int r0 = blockIdx.x * 64, c0 = blockIdx.y * 64;
    __shared__ ushort_t Lt[64][65];
    const int tid = threadIdx.x;
    #pragma unroll
    for (int p = 0; p < 2; ++p) {
        const int i = (tid >> 3) + p * 32;
        const int j8 = (tid & 7) * 8;
        us8 v = *(const us8*)&Sb[(size_t)(r0 + i) * NN + c0 + j8];
        #pragma unroll
        for (int e = 0; e < 8; ++e) Lt[i][j8 + e] = v[e];
    }
    __syncthreads();
    #pragma unroll
    for (int p = 0; p < 2; ++p) {
        const int jj = (tid >> 3) + p * 32;
        const int i8 = (tid & 7) * 8;
        us8 v;
        #pragma unroll
        for (int e = 0; e < 8; ++e) v[e] = Lt[i8 + e][jj];
        *(us8*)&SbT[(size_t)(c0 + jj) * NN + r0 + i8] = v;
    }
}

// ---------------------------------------------------------------------------
// Pack: xbT[b][ft][n] = bf16(x[b][n][ft])   (per-batch transpose)
// ---------------------------------------------------------------------------
__global__ __launch_bounds__(256)
void k_pack_x(const float* __restrict__ x, ushort_t* __restrict__ xbT) {
    const int nc = blockIdx.x * 64;
    const int b  = blockIdx.y;
    __shared__ ushort_t Lt[FT][65];
    const int tid = threadIdx.x;
    const float* __restrict__ xb = x + (size_t)b * NN * FT;
    #pragma unroll
    for (int p = 0; p < 12; ++p) {
        const int id = tid + 256 * p;      // 0..3071
        const int nn = id / 48;
        const int f4 = (id % 48) * 4;
        const float4 v = *(const float4*)&xb[(size_t)(nc + nn) * FT + f4];
        Lt[f4 + 0][nn] = f2b(v.x);
        Lt[f4 + 1][nn] = f2b(v.y);
        Lt[f4 + 2][nn] = f2b(v.z);
        Lt[f4 + 3][nn] = f2b(v.w);
    }
    __syncthreads();
    #pragma unroll
    for (int p = 0; p < 6; ++p) {
        const int id = tid + 256 * p;      // 0..1535
        const int ft = id >> 3;
        const int n8 = (id & 7) * 8;
        us8 v;
        #pragma unroll
        for (int e = 0; e < 8; ++e) v[e] = Lt[ft][n8 + e];
        *(us8*)&xbT[((size_t)b * FT + ft) * NN + nc + n8] = v;
    }
}

// ---------------------------------------------------------------------------
// Phase 2: T2b = bf16(2*S@S - I). MFMA bf16, 64x64 tile, BK=64.
// 3-stage pipeline: global->regs issued 2 iters ahead, regs->LDS 1 iter
// ahead, LDS double-buffered, one barrier per K-iter.
// ---------------------------------------------------------------------------
__global__ __launch_bounds__(256, 4)
void k_t2(const ushort_t* __restrict__ Sb, const ushort_t* __restrict__ SbT,
          ushort_t* __restrict__ T2b) {
    const int m0 = blockIdx.x * 64;     // cols
    const int n0 = blockIdx.y * 64;     // rows
    __shared__ __align__(16) ushort_t As[2][64 * 64];
    __shared__ __align__(16) ushort_t Bs[2][64 * 64];
    const int tid = threadIdx.x;
    const int lane = tid & 63, w = tid >> 6;
    const int l15 = lane & 15, q = lane >> 4, l7 = lane & 7;
    const int n0w = (w & 1) * 32, m0w = (w >> 1) * 32;
    const int sr = tid >> 3;            // staging row 0..31 (+32)
    const int sc = tid & 7;             // staging chunk 0..7

    f32x4 acc[2][2];
    #pragma unroll
    for (int i = 0; i < 2; ++i)
        #pragma unroll
        for (int j = 0; j < 2; ++j) acc[i][j] = {0.f, 0.f, 0.f, 0.f};

    us8 avA[2], bvA[2], avB[2], bvB[2];

#define T2_LOAD(l0, av, bv)                                              \
    { _Pragma("unroll") for (int p = 0; p < 2; ++p) {                    \
        const int row_ = sr + 32 * p;                                    \
        av[p] = *(const us8*)&Sb[(size_t)(n0 + row_) * NN + (l0) + sc * 8];  \
        bv[p] = *(const us8*)&SbT[(size_t)(m0 + row_) * NN + (l0) + sc * 8]; \
      } }

#define T2_STORE(bufi, av, bv)                                           \
    { _Pragma("unroll") for (int p = 0; p < 2; ++p) {                    \
        const int row_ = sr + 32 * p;                                    \
        const int cs_ = (sc ^ (row_ & 7)) * 8;                           \
        *(us8*)&As[bufi][row_ * 64 + cs_] = av[p];                       \
        *(us8*)&Bs[bufi][row_ * 64 + cs_] = bv[p];                       \
      } }

#define T2_MFMA(bufi)                                                    \
    { _Pragma("unroll") for (int s = 0; s < 2; ++s) {                    \
        short8 a_[2], b_[2];                                             \
        const int u_ = ((s * 4 + q) ^ l7) * 8;                           \
        _Pragma("unroll") for (int i = 0; i < 2; ++i)                    \
            a_[i] = *(const short8*)&As[bufi][(n0w + i * 16 + l15) * 64 + u_]; \
        _Pragma("unroll") for (int j = 0; j < 2; ++j)                    \
            b_[j] = *(const short8*)&Bs[bufi][(m0w + j * 16 + l15) * 64 + u_]; \
        _Pragma("unroll") for (int i = 0; i < 2; ++i)                    \
            _Pragma("unroll") for (int j = 0; j < 2; ++j)                \
                acc[i][j] = __builtin_amdgcn_mfma_f32_16x16x32_bf16(a_[i], b_[j], acc[i][j], 0, 0, 0); \
      } }

    T2_LOAD(0, avA, bvA);
    T2_LOAD(64, avB, bvB);
    T2_STORE(0, avA, bvA);

    for (int it = 0; it < 32; it += 2) {
        __syncthreads();
        if (it < 30) T2_LOAD((it + 2) * 64, avA, bvA);
        T2_MFMA(0);
        T2_STORE(1, avB, bvB);
        __syncthreads();
        if (it < 29) T2_LOAD((it + 3) * 64, avB, bvB);
        T2_MFMA(1);
        if (it < 30) T2_STORE(0, avA, bvA);
    }
#undef T2_LOAD
#undef T2_STORE
#undef T2_MFMA

    #pragma unroll
    for (int i = 0; i < 2; ++i)
        #pragma unroll
        for (int j = 0; j < 2; ++j)
            #pragma unroll
            for (int r = 0; r < 4; ++r) {
                const int ng = n0 + n0w + i * 16 + q * 4 + r;
                const int mg = m0 + m0w + j * 16 + l15;
                const float v = 2.0f * acc[i][j][r] - (ng == mg ? 1.0f : 0.0f);
                T2b[(size_t)ng * NN + mg] = f2b(v);
            }
}

// ---------------------------------------------------------------------------
// Phase 3: rhs[k1][b][m][ft] = sum_n (P_k1 . att_b)[n,m] * x[b,n,ft]  (MFMA)
// Block: 32 m x 192 ft, BOTH k1 fused (att read once). BK=64.
// 3-stage pipeline: global->regs 2 iters ahead (full-iter latency window),
// Hadamard+regs->LDS 1 iter ahead (packed v_cvt_pk_bf16_f32), LDS dbuf,
// one barrier per iter. VGPR is free here: grid caps occupancy at 2 blk/CU.
// ---------------------------------------------------------------------------
__global__ __launch_bounds__(256, 2)
void k_rhs(const ushort_t* __restrict__ Sb, const ushort_t* __restrict__ T2b,
           const float* __restrict__ att, const ushort_t* __restrict__ xbT,
           float* __restrict__ rhs) {
    const int m0 = blockIdx.x * 32;
    const int b  = blockIdx.y;
    __shared__ __align__(16) ushort_t As[2][2 * 32 * 64];  // 16 KB: [buf][k1][m][nn swz]
    __shared__ __align__(16) ushort_t Xs[2][FT * 64];      // 48 KB
    const int tid = threadIdx.x;
    const int lane = tid & 63, w = tid >> 6;
    const int l15 = lane & 15, q = lane >> 4, l7 = lane & 7, l3 = lane >> 3;
    const int k1 = w & 1, ft0 = (w >> 1) * 96;
    const float* __restrict__ attb = att + (size_t)b * NN * NN;

    // W-staging assignment: half-block per k1; 8 m-groups x 16 nn-groups
    const int k1s = tid >> 7;
    const int uu  = tid & 127;
    const int m4  = (uu & 7) * 4;
    const int nn4 = (uu >> 3) * 4;
    const ushort_t* __restrict__ Pk = k1s ? T2b : Sb;

    f32x4 acc[2][6];
    #pragma unroll
    for (int i = 0; i < 2; ++i)
        #pragma unroll
        for (int t = 0; t < 6; ++t) acc[i][t] = {0.f, 0.f, 0.f, 0.f};

    us8   xvA[6], xvB[6];
    us4   pvA[4], pvB[4];
    f32x4 avA[4], avB[4];

#define RHS_LOAD(nc, xv, pv, av)                                         \
    { _Pragma("unroll") for (int p = 0; p < 6; ++p) {                    \
        const int row_ = (w * 6 + p) * 8 + l3;                           \
        xv[p] = *(const us8*)&xbT[((size_t)b * FT + row_) * NN + (nc) + l7 * 8]; \
      }                                                                  \
      _Pragma("unroll") for (int r = 0; r < 4; ++r) {                    \
        const int nn_ = (nc) + nn4 + r;                                  \
        pv[r] = *(const us4*)&Pk[(size_t)nn_ * NN + m0 + m4];            \
        av[r] = *(const f32x4*)&attb[(size_t)nn_ * NN + m0 + m4];        \
      } }

#define RHS_STORE(bufi, xv, pv, av)                                      \
    { _Pragma("unroll") for (int p = 0; p < 6; ++p) {                    \
        const int row_ = (w * 6 + p) * 8 + l3;                           \
        *(us8*)&Xs[bufi][row_ * 64 + (l7 ^ l3) * 8] = xv[p];             \
      }                                                                  \
      _Pragma("unroll") for (int c = 0; c < 4; ++c) {                    \
        const float w0_ = b2f(pv[0][c]) * av[0][c];                      \
        const float w1_ = b2f(pv[1][c]) * av[1][c];                      \
        const float w2_ = b2f(pv[2][c]) * av[2][c];                      \
        const float w3_ = b2f(pv[3][c]) * av[3][c];                      \
        unsigned int u01_, u23_;                                         \
        asm("v_cvt_pk_bf16_f32 %0, %1, %2" : "=v"(u01_) : "v"(w0_), "v"(w1_)); \
        asm("v_cvt_pk_bf16_f32 %0, %1, %2" : "=v"(u23_) : "v"(w2_), "v"(w3_)); \
        const int rowm_ = m4 + c;                                        \
        const int off_ = (((nn4 >> 3) ^ (rowm_ & 7)) * 8) + (nn4 & 4);   \
        *(uint2*)&As[bufi][(k1s * 32 + rowm_) * 64 + off_] = make_uint2(u01_, u23_); \
      } }

#define RHS_MFMA(bufi)                                                   \
    { _Pragma("unroll") for (int s = 0; s < 2; ++s) {                    \
        short8 a_[2], bb_[6];                                            \
        _Pragma("unroll") for (int i = 0; i < 2; ++i) {                  \
            const int row_ = i * 16 + l15;                               \
            a_[i] = *(const short8*)&As[bufi][(k1 * 32 + row_) * 64 + (((s * 4 + q) ^ l7) * 8)]; \
        }                                                                \
        _Pragma("unroll") for (int t = 0; t < 6; ++t) {                  \
            const int col_ = ft0 + t * 16 + l15;                         \
            const int u_ = ((s * 4 + q) ^ (col_ & 7)) * 8;               \
            bb_[t] = *(const short8*)&Xs[bufi][col_ * 64 + u_];          \
        }                                                                \
        _Pragma("unroll") for (int i = 0; i < 2; ++i)                    \
            _Pragma("unroll") for (int t = 0; t < 6; ++t)                \
                acc[i][t] = __builtin_amdgcn_mfma_f32_16x16x32_bf16(a_[i], bb_[t], acc[i][t], 0, 0, 0); \
      } }

    // ---- prologue: chunks 0 and 1 in flight; chunk 0 staged to LDS[0] ----
    RHS_LOAD(0, xvA, pvA, avA);
    RHS_LOAD(64, xvB, pvB, avB);
    RHS_STORE(0, xvA, pvA, avA);

    for (int it = 0; it < 32; it += 2) {
        __syncthreads();
        if (it < 30) RHS_LOAD((it + 2) * 64, xvA, pvA, avA);
        RHS_MFMA(0);
        RHS_STORE(1, xvB, pvB, avB);
        __syncthreads();
        if (it < 29) RHS_LOAD((it + 3) * 64, xvB, pvB, avB);
        RHS_MFMA(1);
        if (it < 30) RHS_STORE(0, xvA, pvA, avA);
    }
#undef RHS_LOAD
#undef RHS_STORE
#undef RHS_MFMA

    float* __restrict__ op = rhs + ((size_t)(k1 * BATCH + b)) * NN * FT;
    #pragma unroll
    for (int i = 0; i < 2; ++i)
        #pragma unroll
        for (int t = 0; t < 6; ++t)
            #pragma unroll
            for (int r = 0; r < 4; ++r) {
                const int mg = m0 + i * 16 + q * 4 + r;
                const int ftg = ft0 + t * 16 + l15;
                op[(size_t)mg * FT + ftg] = acc[i][t][r];
            }
}

// ---------------------------------------------------------------------------
// Phase 4: out[b,m,o,t] = relu( th0.(att[b,m,m]*x[b,m]) + th1.rhs1 + th2.rhs2 )
// ---------------------------------------------------------------------------
__global__ __launch_bounds__(128)
void k_out(const float* __restrict__ x, const float* __restrict__ att,
           const float* __restrict__ theta, const float* __restrict__ rhs,
           float* __restrict__ out) {
    const int m = blockIdx.x & (NN - 1);
    const int b = blockIdx.x >> 11;
    __shared__ float xr[FT], r1[FT], r2[FT];
    __shared__ float th[3 * FIN * FOUT];
    const int tid = threadIdx.x;

    const float* __restrict__ xb = x + ((size_t)b * NN + m) * FT;
    const float* __restrict__ p1 = rhs + ((size_t)0 * BATCH + b) * NN * FT + (size_t)m * FT;
    const float* __restrict__ p2 = rhs + ((size_t)1 * BATCH + b) * NN * FT + (size_t)m * FT;
    const float a0 = att[((size_t)b * NN + m) * NN + m];

    for (int i = tid; i < FT; i += 128) {
        xr[i] = xb[i] * a0;
        r1[i] = p1[i];
        r2[i] = p2[i];
    }
    for (int i = tid; i < 3 * FIN * FOUT; i += 128) th[i] = theta[i];
    __syncthreads();

    float* __restrict__ ob = out + ((size_t)b * NN + m) * OT;
    for (int idx = tid; idx < OT; idx += 128) {
        const int o = idx / TT, t = idx % TT;
        float acc = 0.0f;
        #pragma unroll
        for (int f = 0; f < FIN; ++f) {
            const int ft = f * TT + t;
            acc += th[f * FOUT + o] * xr[ft];
            acc += th[512 + f * FOUT + o] * r1[ft];
            acc += th[1024 + f * FOUT + o] * r2[ft];
        }
        ob[idx] = fmaxf(acc, 0.0f);
    }
}

// ---------------------------------------------------------------------------
extern "C" void kernel_launch(void* const* d_in, const int* in_sizes, int n_in,
                              void* d_out, int out_size, void* d_ws, size_t ws_size,
                              hipStream_t stream) {
    const float* x     = (const float*)d_in[0]; // (B,N,F_in,T) fp32
    const float* att   = (const float*)d_in[1]; // (B,N,N) fp32
    const float* E     = (const float*)d_in[2]; // (N,16) fp32
    const float* theta = (const float*)d_in[3]; // (K,F_in,F_out) fp32
    float* out = (float*)d_out;                 // (B,N,F_out,T) fp32

    // Workspace: Sb | SbT | T2b (bf16 N*N each) | xbT (bf16 B*FT*N) | rhs (fp32)
    ushort_t* Sb  = (ushort_t*)d_ws;
    ushort_t* SbT = Sb  + (size_t)NN * NN;
    ushort_t* T2b = SbT + (size_t)NN * NN;
    ushort_t* xbT = T2b + (size_t)NN * NN;
    float*    rhs = (float*)(xbT + (size_t)BATCH * FT * NN);   // ~54 MB total

    k_supports<<<NN, 256, 0, stream>>>(E, Sb);
    k_pack_st<<<dim3(32, 32), 256, 0, stream>>>(Sb, SbT);
    k_pack_x<<<dim3(32, BATCH), 256, 0, stream>>>(x, xbT);
    k_t2<<<dim3(32, 32), 256, 0, stream>>>(Sb, SbT, T2b);
    k_rhs<<<dim3(64, BATCH), 256, 0, stream>>>(Sb, T2b, att, xbT, rhs);
    k_out<<<BATCH * NN, 128, 0, stream>>>(x, att, theta, rhs, out);
}